// Round 12
// baseline (433.034 us; speedup 1.0000x reference)
//
#include <hip/hip_runtime.h>
#include <math.h>

#define B_    16
#define C_    256
#define H_    200
#define W_    200
#define NBOX  100
#define HID   256
#define OUTK  7
#define ROI_DIM 12544        // C_ * 49
#define KP    37632          // 3 * ROI_DIM, plane-major: [ah | ah | al] x [bh | bl | bh]
#define NCLS  4

struct __attribute__((packed, aligned(4))) f2u { float x, y; };

typedef __attribute__((ext_vector_type(8))) short short8v;
typedef __attribute__((ext_vector_type(4))) float f32x4;

static __device__ __forceinline__ unsigned short f2bf(float f) {
  unsigned u = __float_as_uint(f);
  return (unsigned short)((u + 0x7FFFu + ((u >> 16) & 1u)) >> 16);   // RNE
}
static __device__ __forceinline__ float bf2f(unsigned short h) {
  return __uint_as_float(((unsigned)h) << 16);
}

static __device__ __forceinline__ void gload_lds16(const void* g, void* l) {
  __builtin_amdgcn_global_load_lds(
      (const __attribute__((address_space(1))) unsigned*)g,
      (__attribute__((address_space(3))) unsigned*)l, 16, 0, 0);
}

// ---------------------------------------------------------------- K1: ROI align — R7 skeleton, width-16 DMA (8 instrs/channel vs 28)
// Block = 1 wave = (box, 8-channel group). Per channel: [28][68]-float window
// (base xbase = min(xlo&~3, 132): 16B-aligned, always in-row, covers all taps)
// staged by 8 global_load_lds width=16 (lane -> slot s=64k+lane -> row s/17,
// group s%17; dest linear lane*16; 8KB buffer absorbs tail spill). Double-
// buffered, counted vmcnt(8). Outstanding vmem ops drop 56 -> 16: clean test
// of the issue/queue-pressure hypothesis for the ~290us floor.
// Output: plane-major split-bf16 (coalesced 98B plane stores).
__global__ __launch_bounds__(64) void roi_pool_kernel(
    const float* __restrict__ feat, const float* __restrict__ boxes,
    unsigned short* __restrict__ Ap)
{
  __shared__ float tile[2][2048];      // 2 x 8KB: [28][68] logical + pad
  __shared__ int   rowoff_s[28];
  __shared__ int   ixs_s[14];
  __shared__ float flys_s[14], flxs_s[14];

  int raw = blockIdx.x;
  int g   = raw & 31;           // channel group: channels [g*8, g*8+8); g%8 == XCD slot
  int bn  = raw >> 5;           // 0..1599
  int b   = bn / NBOX;

  const float* bx = boxes + (size_t)bn * 4;
  float px1 = bx[0] - 0.5f, py1 = bx[1] - 0.5f;
  float px2 = bx[2] - 0.5f, py2 = bx[3] - 0.5f;
  float bh = (py2 - py1) * (1.0f / OUTK);
  float bw = (px2 - px1) * (1.0f / OUTK);

  int lane = threadIdx.x;
  if (lane < 14) {
    int i = lane >> 1, s = lane & 1;
    float yy = py1 + ((float)i + ((float)s + 0.5f) * 0.5f) * bh;
    float yc = fminf(fmaxf(yy, 0.0f), (float)(H_ - 1));
    int y0 = min((int)floorf(yc), H_ - 2);
    rowoff_s[2 * lane]     = y0 * W_;
    rowoff_s[2 * lane + 1] = y0 * W_ + W_;
    flys_s[lane] = yc - (float)y0;
  } else if (lane >= 16 && lane < 30) {
    int t = lane - 16;
    int j = t >> 1, s = t & 1;
    float xx = px1 + ((float)j + ((float)s + 0.5f) * 0.5f) * bw;
    float xc = fminf(fmaxf(xx, 0.0f), (float)(W_ - 1));
    int x0 = min((int)floorf(xc), W_ - 2);
    ixs_s[t]  = x0;
    flxs_s[t] = xc - (float)x0;
  }
  asm volatile("s_waitcnt lgkmcnt(0)" ::: "memory");   // same-wave table visibility

  int xbase = min(ixs_s[0] & ~3, 132);   // aligned window start; [xbase, xbase+67] covers all taps

  int off[8];                            // per-lane DMA source offsets (floats)
  #pragma unroll
  for (int k = 0; k < 8; ++k) {
    int s   = k * 64 + lane;
    int r17 = s / 17;
    int grp = s - r17 * 17;
    off[k] = rowoff_s[min(r17, 27)] + xbase + grp * 4;
  }

  // per-lane bin constants, reused across all 8 channels
  int l49 = lane < 49 ? lane : 0;
  int bi = l49 / 7, bj = l49 - bi * 7;
  float ly0 = flys_s[2 * bi],     hy0 = 1.0f - ly0;
  float ly1 = flys_s[2 * bi + 1], hy1 = 1.0f - ly1;
  float lx0 = flxs_s[2 * bj],     hx0 = 1.0f - lx0;
  float lx1 = flxs_s[2 * bj + 1], hx1 = 1.0f - lx1;
  int xo0 = ixs_s[2 * bj] - xbase;
  int xo1 = ixs_s[2 * bj + 1] - xbase;
  int r0  = 4 * bi;

  int c0 = g * 8;
  const char* fc = (const char*)(feat + (size_t)b * (C_ * H_ * W_) + (size_t)c0 * (H_ * W_));
  // plane-major output: A'[row] = [ah(12544) | ah(12544) | al(12544)]
  unsigned short* pw0 = Ap + (size_t)bn * KP + (size_t)(c0 * 49 + l49);

  auto issue = [&](int n, int bufsel) {
    const char* cb = fc + (size_t)n * (H_ * W_ * 4);
    char* lb = (char*)tile[bufsel];
    #pragma unroll
    for (int k = 0; k < 8; ++k)
      gload_lds16(cb + (size_t)off[k] * 4, lb + k * 1024);
  };

  issue(0, 0);                           // prologue: channel 0 -> buf0

  #pragma unroll 1
  for (int n = 0; n < 8; ++n) {
    if (n < 7) {
      issue(n + 1, (n + 1) & 1);
      asm volatile("s_waitcnt vmcnt(8)" ::: "memory");   // current channel ready
    } else {
      asm volatile("s_waitcnt vmcnt(0)" ::: "memory");
    }
    __builtin_amdgcn_sched_barrier(0);
    const float* T = tile[n & 1];
    if (lane < 49) {
      f2u a0 = *(const f2u*)(T + (r0 + 0) * 68 + xo0);
      f2u a1 = *(const f2u*)(T + (r0 + 1) * 68 + xo0);
      f2u b0 = *(const f2u*)(T + (r0 + 0) * 68 + xo1);
      f2u b1 = *(const f2u*)(T + (r0 + 1) * 68 + xo1);
      f2u c2 = *(const f2u*)(T + (r0 + 2) * 68 + xo0);
      f2u c3 = *(const f2u*)(T + (r0 + 3) * 68 + xo0);
      f2u d2 = *(const f2u*)(T + (r0 + 2) * 68 + xo1);
      f2u d3 = *(const f2u*)(T + (r0 + 3) * 68 + xo1);
      float sum = hy0 * (hx0 * a0.x + lx0 * a0.y) + ly0 * (hx0 * a1.x + lx0 * a1.y)
                + hy0 * (hx1 * b0.x + lx1 * b0.y) + ly0 * (hx1 * b1.x + lx1 * b1.y)
                + hy1 * (hx0 * c2.x + lx0 * c2.y) + ly1 * (hx0 * c3.x + lx0 * c3.y)
                + hy1 * (hx1 * d2.x + lx1 * d2.y) + ly1 * (hx1 * d3.x + lx1 * d3.y);
      float s = sum * 0.25f;
      unsigned short hi = f2bf(s);
      unsigned short lo = f2bf(s - bf2f(hi));
      unsigned short* p = pw0 + n * 49;
      p[0]         = hi;    // plane 0: ah
      p[ROI_DIM]   = hi;    // plane 1: ah (dup)
      p[2*ROI_DIM] = lo;    // plane 2: al
    }
  }
}

// ---------------------------------------------------------------- K1b: w_roi -> split-bf16 B' plane-major [bh | bl | bh]
__global__ __launch_bounds__(256) void wconv_kernel(
    const float* __restrict__ w, unsigned short* __restrict__ Bp)
{
  int i = blockIdx.x * 256 + threadIdx.x;     // over 256*12544
  int n = i / ROI_DIM, k = i - n * ROI_DIM;
  float f = w[i];
  unsigned short hi = f2bf(f);
  unsigned short lo = f2bf(f - bf2f(hi));
  unsigned short* r = Bp + (size_t)n * KP + k;
  r[0]         = hi;    // plane 0: pairs with ah -> ah*bh
  r[ROI_DIM]   = lo;    // plane 1: pairs with ah -> ah*bl
  r[2*ROI_DIM] = hi;    // plane 2: pairs with al -> al*bh
}

// ---------------------------------------------------------------- K3: bf16 MFMA GEMM, full-N tile, partials (no atomics)
#define GBM 64
#define GBN 256
#define GBK 64
#define KSP 21
#define KT  28        // (KP/GBK)/KSP = 588/21
__global__ __launch_bounds__(256) void gemm_kernel(
    const unsigned short* __restrict__ Ap,
    const unsigned short* __restrict__ Bp,
    float* __restrict__ Cpart)
{
  __shared__ __align__(16) short As[GBM * GBK];   // 8 KB, swizzled chunks
  __shared__ __align__(16) short Bs[GBN * GBK];   // 32 KB

  int tid  = threadIdx.x;
  int lane = tid & 63;
  int w    = tid >> 6;
  int wr   = w >> 1, wc = w & 1;          // wave: rows wr*32, cols wc*128
  int m0 = blockIdx.x * GBM;
  int z  = blockIdx.y;
  int kbase = z * (GBK * KT);

  f32x4 acc[2][8];
  #pragma unroll
  for (int mi = 0; mi < 2; ++mi)
    #pragma unroll
    for (int nj = 0; nj < 8; ++nj)
      acc[mi][nj] = (f32x4){0.f, 0.f, 0.f, 0.f};

  for (int kt = 0; kt < KT; ++kt) {
    int kg = kbase + kt * GBK;
    __syncthreads();
    #pragma unroll
    for (int r = 0; r < 2; ++r) {          // stage A: 512 chunks of 16B
      int q = tid + r * 256;
      int row = q >> 3, c16 = q & 7;
      int kc16 = c16 ^ (row & 7);
      short8v v = *(const short8v*)(Ap + (size_t)(m0 + row) * KP + kg + kc16 * 8);
      *(short8v*)(As + row * GBK + c16 * 8) = v;
    }
    #pragma unroll
    for (int r = 0; r < 8; ++r) {          // stage B: 2048 chunks (all 256 rows)
      int q = tid + r * 256;
      int row = q >> 3, c16 = q & 7;
      int kc16 = c16 ^ (row & 7);
      short8v v = *(const short8v*)(Bp + (size_t)row * KP + kg + kc16 * 8);
      *(short8v*)(Bs + row * GBK + c16 * 8) = v;
    }
    __syncthreads();
    #pragma unroll
    for (int kk = 0; kk < 2; ++kk) {       // two K=32 steps per tile
      short8v af[2], bf[8];
      #pragma unroll
      for (int mi = 0; mi < 2; ++mi) {
        int row = wr * 32 + mi * 16 + (lane & 15);
        int c16 = (kk * 4 + (lane >> 4)) ^ (row & 7);
        af[mi] = *(const short8v*)(As + row * GBK + c16 * 8);
      }
      #pragma unroll
      for (int nj = 0; nj < 8; ++nj) {
        int row = wc * 128 + nj * 16 + (lane & 15);
        int c16 = (kk * 4 + (lane >> 4)) ^ (row & 7);
        bf[nj] = *(const short8v*)(Bs + row * GBK + c16 * 8);
      }
      #pragma unroll
      for (int mi = 0; mi < 2; ++mi)
        #pragma unroll
        for (int nj = 0; nj < 8; ++nj)
          acc[mi][nj] = __builtin_amdgcn_mfma_f32_16x16x32_bf16(
              af[mi], bf[nj], acc[mi][nj], 0, 0, 0);
    }
  }
  // epilogue: plain stores to partial buffer (D col=lane&15, row=(lane>>4)*4+reg)
  float* part = Cpart + (size_t)z * (B_ * NBOX * HID);
  int cn = lane & 15, rg = lane >> 4;
  #pragma unroll
  for (int mi = 0; mi < 2; ++mi)
    #pragma unroll
    for (int nj = 0; nj < 8; ++nj)
      #pragma unroll
      for (int r = 0; r < 4; ++r) {
        int row = m0 + wr * 32 + mi * 16 + rg * 4 + r;
        int col = wc * 128 + nj * 16 + cn;
        part[(size_t)row * HID + col] = acc[mi][nj][r];
      }
}

// ---------------------------------------------------------------- K3b: tokens = bias + sum of partials
__global__ __launch_bounds__(256) void reduce_kernel(
    const float* __restrict__ Cpart, const float* __restrict__ b_roi,
    float* __restrict__ tokens)
{
  int i = blockIdx.x * 256 + threadIdx.x;   // 409600
  float a = b_roi[i & 255];
  #pragma unroll
  for (int z = 0; z < KSP; ++z) a += Cpart[(size_t)z * (B_ * NBOX * HID) + i];
  tokens[i] = a;
}

// ---------------------------------------------------------------- K4a: attention per (batch, head) -> ctx
__global__ __launch_bounds__(256) void attn_kernel(
    const float* __restrict__ tokens, const float* __restrict__ sev_q,
    const float* __restrict__ w_in,  const float* __restrict__ b_in,
    float* __restrict__ ctx)
{
  __shared__ float qh_s[64], qkv_s[256], att_s[128], tbar_s[256], red_s[2];
  int bh = blockIdx.x;
  int b = bh >> 2, h = bh & 3;
  int tid = threadIdx.x;
  const float* tok = tokens + (size_t)b * NBOX * HID;

  if (tid < 64) {                      // qh[d] = sev_q . Wq[h*64+d] + bq
    const float* wq = w_in + (size_t)(h * 64 + tid) * HID;
    float a = 0.0f;
    for (int e = 0; e < HID; ++e) a += sev_q[e] * wq[e];
    qh_s[tid] = a + b_in[h * 64 + tid];
  }
  __syncthreads();
  {                                    // qkv[e] = sum_d qh[d] * Wk[h*64+d][e]
    float a = 0.0f;
    for (int d = 0; d < 64; ++d)
      a += qh_s[d] * w_in[(size_t)(256 + h * 64 + d) * HID + tid];
    qkv_s[tid] = a;
  }
  if (tid == 0) {                      // qkb
    float a = 0.0f;
    for (int d = 0; d < 64; ++d) a += qh_s[d] * b_in[256 + h * 64 + d];
    red_s[0] = a;
  }
  __syncthreads();
  if (tid < NBOX) {                    // scores
    const float4* tr = (const float4*)(tok + (size_t)tid * HID);
    const float4* qv = (const float4*)qkv_s;
    float a = 0.0f;
    for (int e = 0; e < 64; ++e) {
      float4 t4 = tr[e], q4 = qv[e];
      a += t4.x * q4.x + t4.y * q4.y + t4.z * q4.z + t4.w * q4.w;
    }
    att_s[tid] = (a + red_s[0]) * 0.125f;
  }
  __syncthreads();
  if (tid == 0) {                      // softmax (serial; 100 elems)
    float mx = -1e30f;
    for (int t = 0; t < NBOX; ++t) mx = fmaxf(mx, att_s[t]);
    float sm = 0.0f;
    for (int t = 0; t < NBOX; ++t) { float e = expf(att_s[t] - mx); att_s[t] = e; sm += e; }
    red_s[1] = 1.0f / sm;
  }
  __syncthreads();
  {                                    // tbar[e] = inv * sum_t att[t]*tok[t][e]
    float a = 0.0f;
    for (int t = 0; t < NBOX; ++t) a += att_s[t] * tok[(size_t)t * HID + tid];
    tbar_s[tid] = a * red_s[1];
  }
  __syncthreads();
  if (tid < 64) {                      // ctx[h*64+d] = tbar . Wv[h*64+d] + bv
    const float* wv = w_in + (size_t)(512 + h * 64 + tid) * HID;
    float a = 0.0f;
    for (int e = 0; e < HID; ++e) a += tbar_s[e] * wv[e];
    ctx[(size_t)b * HID + h * 64 + tid] = a + b_in[512 + h * 64 + tid];
  }
}

// ---------------------------------------------------------------- K4b: Wout + LayerNorm + MLP per batch
__global__ __launch_bounds__(256) void mlp_kernel(
    const float* __restrict__ ctx,
    const float* __restrict__ w_out, const float* __restrict__ b_out,
    const float* __restrict__ ln_g,  const float* __restrict__ ln_b,
    const float* __restrict__ w1,    const float* __restrict__ b1,
    const float* __restrict__ w2,    const float* __restrict__ b2,
    float* __restrict__ outp)
{
  __shared__ float o_s[256], x_s[256], h1_s[256], red_s[8];
  int b = blockIdx.x, tid = threadIdx.x;
  const float* cx = ctx + (size_t)b * HID;
  {
    const float* wo = w_out + (size_t)tid * HID;
    float a = 0.0f;
    for (int k = 0; k < HID; ++k) a += cx[k] * wo[k];
    o_s[tid] = a + b_out[tid];
  }
  __syncthreads();
  {
    float v = o_s[tid];
    float s1 = v, s2 = v * v;
    #pragma unroll
    for (int off = 32; off > 0; off >>= 1) {
      s1 += __shfl_down(s1, off);
      s2 += __shfl_down(s2, off);
    }
    if ((tid & 63) == 0) { red_s[(tid >> 6) * 2] = s1; red_s[(tid >> 6) * 2 + 1] = s2; }
    __syncthreads();
    float sum = red_s[0] + red_s[2] + red_s[4] + red_s[6];
    float ssq = red_s[1] + red_s[3] + red_s[5] + red_s[7];
    float mu  = sum * (1.0f / 256.0f);
    float var = ssq * (1.0f / 256.0f) - mu * mu;
    float inv = rsqrtf(var + 1e-5f);
    x_s[tid] = (v - mu) * inv * ln_g[tid] + ln_b[tid];
  }
  __syncthreads();
  {
    const float* wr = w1 + (size_t)tid * HID;
    float a = 0.0f;
    for (int k = 0; k < HID; ++k) a += x_s[k] * wr[k];
    h1_s[tid] = fmaxf(a + b1[tid], 0.0f);
  }
  __syncthreads();
  if (tid < NCLS) {
    const float* wr = w2 + (size_t)tid * HID;
    float a = 0.0f;
    for (int k = 0; k < HID; ++k) a += h1_s[k] * wr[k];
    outp[b * NCLS + tid] = a + b2[tid];
  }
}

// ---------------------------------------------------------------- launch
extern "C" void kernel_launch(void* const* d_in, const int* in_sizes, int n_in,
                              void* d_out, int out_size, void* d_ws, size_t ws_size,
                              hipStream_t stream) {
  (void)in_sizes; (void)n_in; (void)out_size; (void)ws_size;
  const float* feat  = (const float*)d_in[0];
  const float* boxes = (const float*)d_in[1];
  const float* w_roi = (const float*)d_in[2];
  const float* b_roi = (const float*)d_in[3];
  const float* sev_q = (const float*)d_in[4];
  const float* w_in  = (const float*)d_in[5];
  const float* b_in  = (const float*)d_in[6];
  const float* w_out = (const float*)d_in[7];
  const float* b_out = (const float*)d_in[8];
  const float* ln_g  = (const float*)d_in[9];
  const float* ln_b  = (const float*)d_in[10];
  const float* w1    = (const float*)d_in[11];
  const float* b1    = (const float*)d_in[12];
  const float* w2    = (const float*)d_in[13];
  const float* b2    = (const float*)d_in[14];
  float* out = (float*)d_out;

  unsigned short* Ap = (unsigned short*)d_ws;            // 1600 x 37632 bf16-split (plane-major)
  unsigned short* Bp = Ap + (size_t)B_ * NBOX * KP;      // 256 x 37632
  float* Cpart  = (float*)(Bp + (size_t)HID * KP);       // KSP x 1600 x 256 f32
  float* tokens = Cpart + (size_t)KSP * B_ * NBOX * HID; // 1600 x 256 f32
  float* ctx    = tokens + (size_t)B_ * NBOX * HID;      // 16 x 256 f32

  roi_pool_kernel<<<B_ * NBOX * 32, 64, 0, stream>>>(feat, boxes, Ap);
  wconv_kernel   <<<(HID * ROI_DIM) / 256, 256, 0, stream>>>(w_roi, Bp);
  gemm_kernel    <<<dim3((B_ * NBOX) / GBM, KSP), 256, 0, stream>>>(Ap, Bp, Cpart);
  reduce_kernel  <<<(B_ * NBOX * HID) / 256, 256, 0, stream>>>(Cpart, b_roi, tokens);
  attn_kernel    <<<B_ * 4, 256, 0, stream>>>(tokens, sev_q, w_in, b_in, ctx);
  mlp_kernel     <<<B_, 256, 0, stream>>>(ctx, w_out, b_out, ln_g, ln_b,
                                          w1, b1, w2, b2, out);
}

// Round 13
// 374.978 us; speedup vs baseline: 1.1548x; 1.1548x over previous
//
#include <hip/hip_runtime.h>
#include <math.h>

#define B_    16
#define C_    256
#define H_    200
#define W_    200
#define NBOX  100
#define HID   256
#define OUTK  7
#define ROI_DIM 12544        // C_ * 49
#define KP    37632          // 3 * ROI_DIM  (split-bf16 interleave: [ah,ah,al]x[bh,bl,bh])
#define NCLS  4

struct __attribute__((packed, aligned(4))) f2u { float x, y; };

typedef __attribute__((ext_vector_type(8))) short short8v;
typedef __attribute__((ext_vector_type(4))) float f32x4;

static __device__ __forceinline__ unsigned short f2bf(float f) {
  unsigned u = __float_as_uint(f);
  return (unsigned short)((u + 0x7FFFu + ((u >> 16) & 1u)) >> 16);   // RNE
}
static __device__ __forceinline__ float bf2f(unsigned short h) {
  return __uint_as_float(((unsigned)h) << 16);
}

static __device__ __forceinline__ void gload_lds4(const void* g, void* l) {
  __builtin_amdgcn_global_load_lds(
      (const __attribute__((address_space(1))) unsigned*)g,
      (__attribute__((address_space(3))) unsigned*)l, 4, 0, 0);
}

// ---------------------------------------------------------------- K1: ROI align — R7 structure, L2-epoch dispatch order
// Block = 1 wave = (img, channel-half, box, 8-channel group g16).
// XCD = blockIdx%8 = g16%8 -> per-XCD concurrent footprint = 16 channel-maps
// = 2.56MB < 4MB L2 (was 32 maps = 5.1MB, thrashing). All 100 boxes of an
// (image, half) epoch run while those maps are L2-resident, so the ~3.25x
// box-overlap reuse becomes L2 hits instead of L3 refills.
__global__ __launch_bounds__(64) void roi_pool_kernel(
    const float* __restrict__ feat, const float* __restrict__ boxes,
    unsigned short* __restrict__ Ap)
{
  constexpr int SPP = 66;
  __shared__ float tile[2][28][SPP];   // 14.8 KB, wave-private
  __shared__ int   rowoff_s[28];
  __shared__ int   ixs_s[14];
  __shared__ float flys_s[14], flxs_s[14];

  int raw  = blockIdx.x;
  int g16  = raw & 15;          // 8-channel group within half; g16%8 == XCD
  int rest = raw >> 4;          // 0..3199
  int bn_l = rest % NBOX;
  int ih   = rest / NBOX;       // 0..31 = (img, half)
  int half = ih & 1;
  int b    = ih >> 1;
  int bn   = b * NBOX + bn_l;

  const float* bx = boxes + (size_t)bn * 4;
  float px1 = bx[0] - 0.5f, py1 = bx[1] - 0.5f;
  float px2 = bx[2] - 0.5f, py2 = bx[3] - 0.5f;
  float bh = (py2 - py1) * (1.0f / OUTK);
  float bw = (px2 - px1) * (1.0f / OUTK);

  int lane = threadIdx.x;
  if (lane < 14) {
    int i = lane >> 1, s = lane & 1;
    float yy = py1 + ((float)i + ((float)s + 0.5f) * 0.5f) * bh;
    float yc = fminf(fmaxf(yy, 0.0f), (float)(H_ - 1));
    int y0 = min((int)floorf(yc), H_ - 2);
    rowoff_s[2 * lane]     = y0 * W_;
    rowoff_s[2 * lane + 1] = y0 * W_ + W_;
    flys_s[lane] = yc - (float)y0;
  } else if (lane >= 16 && lane < 30) {
    int t = lane - 16;
    int j = t >> 1, s = t & 1;
    float xx = px1 + ((float)j + ((float)s + 0.5f) * 0.5f) * bw;
    float xc = fminf(fmaxf(xx, 0.0f), (float)(W_ - 1));
    int x0 = min((int)floorf(xc), W_ - 2);
    ixs_s[t]  = x0;
    flxs_s[t] = xc - (float)x0;
  }
  asm volatile("s_waitcnt lgkmcnt(0)" ::: "memory");   // same-wave table visibility

  int xlo  = ixs_s[0];
  int span = ixs_s[13] + 2 - xlo;      // <= 64
  bool ld  = lane < span;

  int voff[28];                        // per-lane global byte offsets
  #pragma unroll
  for (int r = 0; r < 28; ++r) voff[r] = (rowoff_s[r] + xlo + lane) * 4;

  // per-lane bin constants, reused across all 8 channels
  int l49 = lane < 49 ? lane : 0;
  int bi = l49 / 7, bj = l49 - bi * 7;
  float ly0 = flys_s[2 * bi],     hy0 = 1.0f - ly0;
  float ly1 = flys_s[2 * bi + 1], hy1 = 1.0f - ly1;
  float lx0 = flxs_s[2 * bj],     hx0 = 1.0f - lx0;
  float lx1 = flxs_s[2 * bj + 1], hx1 = 1.0f - lx1;
  int xo0 = ixs_s[2 * bj] - xlo;
  int xo1 = ixs_s[2 * bj + 1] - xlo;
  int r0  = 4 * bi;

  int c0 = half * 128 + g16 * 8;       // wave's first channel
  const char* fc = (const char*)(feat + (size_t)b * (C_ * H_ * W_) + (size_t)c0 * (H_ * W_));
  unsigned short* pw = Ap + (size_t)bn * KP + (size_t)(c0 * 49 + l49) * 3;

  if (ld) {                            // prologue: DMA channel 0 -> buf0
    #pragma unroll
    for (int r = 0; r < 28; ++r) gload_lds4(fc + voff[r], &tile[0][r][0]);
  }

  #pragma unroll 1
  for (int n = 0; n < 8; ++n) {
    if (n < 7) {                       // issue next channel's DMA -> other buffer
      const char* fn = fc + (size_t)(n + 1) * (H_ * W_ * 4);
      if (ld) {
        #pragma unroll
        for (int r = 0; r < 28; ++r) gload_lds4(fn + voff[r], &tile[(n + 1) & 1][r][0]);
      }
      asm volatile("s_waitcnt vmcnt(28)" ::: "memory");   // current channel ready
    } else {
      asm volatile("s_waitcnt vmcnt(0)" ::: "memory");
    }
    float (*T)[SPP] = tile[n & 1];
    if (lane < 49) {
      f2u a0 = *(const f2u*)&T[r0 + 0][xo0];
      f2u a1 = *(const f2u*)&T[r0 + 1][xo0];
      f2u b0 = *(const f2u*)&T[r0 + 0][xo1];
      f2u b1 = *(const f2u*)&T[r0 + 1][xo1];
      f2u c2 = *(const f2u*)&T[r0 + 2][xo0];
      f2u c3 = *(const f2u*)&T[r0 + 3][xo0];
      f2u d2 = *(const f2u*)&T[r0 + 2][xo1];
      f2u d3 = *(const f2u*)&T[r0 + 3][xo1];
      float sum = hy0 * (hx0 * a0.x + lx0 * a0.y) + ly0 * (hx0 * a1.x + lx0 * a1.y)
                + hy0 * (hx1 * b0.x + lx1 * b0.y) + ly0 * (hx1 * b1.x + lx1 * b1.y)
                + hy1 * (hx0 * c2.x + lx0 * c2.y) + ly1 * (hx0 * c3.x + lx0 * c3.y)
                + hy1 * (hx1 * d2.x + lx1 * d2.y) + ly1 * (hx1 * d3.x + lx1 * d3.y);
      float s = sum * 0.25f;
      unsigned short hi = f2bf(s);
      unsigned short lo = f2bf(s - bf2f(hi));
      pw[0] = hi; pw[1] = hi; pw[2] = lo;
    }
    pw += 49 * 3;
  }
}

// ---------------------------------------------------------------- K1b: w_roi -> split-bf16 B' [bh, bl, bh]
__global__ __launch_bounds__(256) void wconv_kernel(
    const float* __restrict__ w, unsigned short* __restrict__ Bp)
{
  int i = blockIdx.x * 256 + threadIdx.x;     // over 256*12544
  int n = i / ROI_DIM, k = i - n * ROI_DIM;
  float f = w[i];
  unsigned short hi = f2bf(f);
  unsigned short lo = f2bf(f - bf2f(hi));
  unsigned short* r = Bp + (size_t)n * KP + 3 * k;
  r[0] = hi; r[1] = lo; r[2] = hi;
}

// ---------------------------------------------------------------- K3: bf16 MFMA GEMM, full-N tile, partials (no atomics)
#define GBM 64
#define GBN 256
#define GBK 64
#define KSP 21
#define KT  28        // (KP/GBK)/KSP = 588/21
__global__ __launch_bounds__(256) void gemm_kernel(
    const unsigned short* __restrict__ Ap,
    const unsigned short* __restrict__ Bp,
    float* __restrict__ Cpart)
{
  __shared__ __align__(16) short As[GBM * GBK];   // 8 KB, swizzled chunks
  __shared__ __align__(16) short Bs[GBN * GBK];   // 32 KB

  int tid  = threadIdx.x;
  int lane = tid & 63;
  int w    = tid >> 6;
  int wr   = w >> 1, wc = w & 1;          // wave: rows wr*32, cols wc*128
  int m0 = blockIdx.x * GBM;
  int z  = blockIdx.y;
  int kbase = z * (GBK * KT);

  f32x4 acc[2][8];
  #pragma unroll
  for (int mi = 0; mi < 2; ++mi)
    #pragma unroll
    for (int nj = 0; nj < 8; ++nj)
      acc[mi][nj] = (f32x4){0.f, 0.f, 0.f, 0.f};

  for (int kt = 0; kt < KT; ++kt) {
    int kg = kbase + kt * GBK;
    __syncthreads();
    #pragma unroll
    for (int r = 0; r < 2; ++r) {          // stage A: 512 chunks of 16B
      int q = tid + r * 256;
      int row = q >> 3, c16 = q & 7;
      int kc16 = c16 ^ (row & 7);
      short8v v = *(const short8v*)(Ap + (size_t)(m0 + row) * KP + kg + kc16 * 8);
      *(short8v*)(As + row * GBK + c16 * 8) = v;
    }
    #pragma unroll
    for (int r = 0; r < 8; ++r) {          // stage B: 2048 chunks (all 256 rows)
      int q = tid + r * 256;
      int row = q >> 3, c16 = q & 7;
      int kc16 = c16 ^ (row & 7);
      short8v v = *(const short8v*)(Bp + (size_t)row * KP + kg + kc16 * 8);
      *(short8v*)(Bs + row * GBK + c16 * 8) = v;
    }
    __syncthreads();
    #pragma unroll
    for (int kk = 0; kk < 2; ++kk) {       // two K=32 steps per tile
      short8v af[2], bf[8];
      #pragma unroll
      for (int mi = 0; mi < 2; ++mi) {
        int row = wr * 32 + mi * 16 + (lane & 15);
        int c16 = (kk * 4 + (lane >> 4)) ^ (row & 7);
        af[mi] = *(const short8v*)(As + row * GBK + c16 * 8);
      }
      #pragma unroll
      for (int nj = 0; nj < 8; ++nj) {
        int row = wc * 128 + nj * 16 + (lane & 15);
        int c16 = (kk * 4 + (lane >> 4)) ^ (row & 7);
        bf[nj] = *(const short8v*)(Bs + row * GBK + c16 * 8);
      }
      #pragma unroll
      for (int mi = 0; mi < 2; ++mi)
        #pragma unroll
        for (int nj = 0; nj < 8; ++nj)
          acc[mi][nj] = __builtin_amdgcn_mfma_f32_16x16x32_bf16(
              af[mi], bf[nj], acc[mi][nj], 0, 0, 0);
    }
  }
  // epilogue: plain stores to partial buffer (D col=lane&15, row=(lane>>4)*4+reg)
  float* part = Cpart + (size_t)z * (B_ * NBOX * HID);
  int cn = lane & 15, rg = lane >> 4;
  #pragma unroll
  for (int mi = 0; mi < 2; ++mi)
    #pragma unroll
    for (int nj = 0; nj < 8; ++nj)
      #pragma unroll
      for (int r = 0; r < 4; ++r) {
        int row = m0 + wr * 32 + mi * 16 + rg * 4 + r;
        int col = wc * 128 + nj * 16 + cn;
        part[(size_t)row * HID + col] = acc[mi][nj][r];
      }
}

// ---------------------------------------------------------------- K3b: tokens = bias + sum of partials
__global__ __launch_bounds__(256) void reduce_kernel(
    const float* __restrict__ Cpart, const float* __restrict__ b_roi,
    float* __restrict__ tokens)
{
  int i = blockIdx.x * 256 + threadIdx.x;   // 409600
  float a = b_roi[i & 255];
  #pragma unroll
  for (int z = 0; z < KSP; ++z) a += Cpart[(size_t)z * (B_ * NBOX * HID) + i];
  tokens[i] = a;
}

// ---------------------------------------------------------------- K4a: attention per (batch, head) -> ctx
__global__ __launch_bounds__(256) void attn_kernel(
    const float* __restrict__ tokens, const float* __restrict__ sev_q,
    const float* __restrict__ w_in,  const float* __restrict__ b_in,
    float* __restrict__ ctx)
{
  __shared__ float qh_s[64], qkv_s[256], att_s[128], tbar_s[256], red_s[2];
  int bh = blockIdx.x;
  int b = bh >> 2, h = bh & 3;
  int tid = threadIdx.x;
  const float* tok = tokens + (size_t)b * NBOX * HID;

  if (tid < 64) {                      // qh[d] = sev_q . Wq[h*64+d] + bq
    const float* wq = w_in + (size_t)(h * 64 + tid) * HID;
    float a = 0.0f;
    for (int e = 0; e < HID; ++e) a += sev_q[e] * wq[e];
    qh_s[tid] = a + b_in[h * 64 + tid];
  }
  __syncthreads();
  {                                    // qkv[e] = sum_d qh[d] * Wk[h*64+d][e]
    float a = 0.0f;
    for (int d = 0; d < 64; ++d)
      a += qh_s[d] * w_in[(size_t)(256 + h * 64 + d) * HID + tid];
    qkv_s[tid] = a;
  }
  if (tid == 0) {                      // qkb
    float a = 0.0f;
    for (int d = 0; d < 64; ++d) a += qh_s[d] * b_in[256 + h * 64 + d];
    red_s[0] = a;
  }
  __syncthreads();
  if (tid < NBOX) {                    // scores
    const float4* tr = (const float4*)(tok + (size_t)tid * HID);
    const float4* qv = (const float4*)qkv_s;
    float a = 0.0f;
    for (int e = 0; e < 64; ++e) {
      float4 t4 = tr[e], q4 = qv[e];
      a += t4.x * q4.x + t4.y * q4.y + t4.z * q4.z + t4.w * q4.w;
    }
    att_s[tid] = (a + red_s[0]) * 0.125f;
  }
  __syncthreads();
  if (tid == 0) {                      // softmax (serial; 100 elems)
    float mx = -1e30f;
    for (int t = 0; t < NBOX; ++t) mx = fmaxf(mx, att_s[t]);
    float sm = 0.0f;
    for (int t = 0; t < NBOX; ++t) { float e = expf(att_s[t] - mx); att_s[t] = e; sm += e; }
    red_s[1] = 1.0f / sm;
  }
  __syncthreads();
  {                                    // tbar[e] = inv * sum_t att[t]*tok[t][e]
    float a = 0.0f;
    for (int t = 0; t < NBOX; ++t) a += att_s[t] * tok[(size_t)t * HID + tid];
    tbar_s[tid] = a * red_s[1];
  }
  __syncthreads();
  if (tid < 64) {                      // ctx[h*64+d] = tbar . Wv[h*64+d] + bv
    const float* wv = w_in + (size_t)(512 + h * 64 + tid) * HID;
    float a = 0.0f;
    for (int e = 0; e < HID; ++e) a += tbar_s[e] * wv[e];
    ctx[(size_t)b * HID + h * 64 + tid] = a + b_in[512 + h * 64 + tid];
  }
}

// ---------------------------------------------------------------- K4b: Wout + LayerNorm + MLP per batch
__global__ __launch_bounds__(256) void mlp_kernel(
    const float* __restrict__ ctx,
    const float* __restrict__ w_out, const float* __restrict__ b_out,
    const float* __restrict__ ln_g,  const float* __restrict__ ln_b,
    const float* __restrict__ w1,    const float* __restrict__ b1,
    const float* __restrict__ w2,    const float* __restrict__ b2,
    float* __restrict__ outp)
{
  __shared__ float o_s[256], x_s[256], h1_s[256], red_s[8];
  int b = blockIdx.x, tid = threadIdx.x;
  const float* cx = ctx + (size_t)b * HID;
  {
    const float* wo = w_out + (size_t)tid * HID;
    float a = 0.0f;
    for (int k = 0; k < HID; ++k) a += cx[k] * wo[k];
    o_s[tid] = a + b_out[tid];
  }
  __syncthreads();
  {
    float v = o_s[tid];
    float s1 = v, s2 = v * v;
    #pragma unroll
    for (int off = 32; off > 0; off >>= 1) {
      s1 += __shfl_down(s1, off);
      s2 += __shfl_down(s2, off);
    }
    if ((tid & 63) == 0) { red_s[(tid >> 6) * 2] = s1; red_s[(tid >> 6) * 2 + 1] = s2; }
    __syncthreads();
    float sum = red_s[0] + red_s[2] + red_s[4] + red_s[6];
    float ssq = red_s[1] + red_s[3] + red_s[5] + red_s[7];
    float mu  = sum * (1.0f / 256.0f);
    float var = ssq * (1.0f / 256.0f) - mu * mu;
    float inv = rsqrtf(var + 1e-5f);
    x_s[tid] = (v - mu) * inv * ln_g[tid] + ln_b[tid];
  }
  __syncthreads();
  {
    const float* wr = w1 + (size_t)tid * HID;
    float a = 0.0f;
    for (int k = 0; k < HID; ++k) a += x_s[k] * wr[k];
    h1_s[tid] = fmaxf(a + b1[tid], 0.0f);
  }
  __syncthreads();
  if (tid < NCLS) {
    const float* wr = w2 + (size_t)tid * HID;
    float a = 0.0f;
    for (int k = 0; k < HID; ++k) a += h1_s[k] * wr[k];
    outp[b * NCLS + tid] = a + b2[tid];
  }
}

// ---------------------------------------------------------------- launch
extern "C" void kernel_launch(void* const* d_in, const int* in_sizes, int n_in,
                              void* d_out, int out_size, void* d_ws, size_t ws_size,
                              hipStream_t stream) {
  (void)in_sizes; (void)n_in; (void)out_size; (void)ws_size;
  const float* feat  = (const float*)d_in[0];
  const float* boxes = (const float*)d_in[1];
  const float* w_roi = (const float*)d_in[2];
  const float* b_roi = (const float*)d_in[3];
  const float* sev_q = (const float*)d_in[4];
  const float* w_in  = (const float*)d_in[5];
  const float* b_in  = (const float*)d_in[6];
  const float* w_out = (const float*)d_in[7];
  const float* b_out = (const float*)d_in[8];
  const float* ln_g  = (const float*)d_in[9];
  const float* ln_b  = (const float*)d_in[10];
  const float* w1    = (const float*)d_in[11];
  const float* b1    = (const float*)d_in[12];
  const float* w2    = (const float*)d_in[13];
  const float* b2    = (const float*)d_in[14];
  float* out = (float*)d_out;

  unsigned short* Ap = (unsigned short*)d_ws;            // 1600 x 37632 bf16-split
  unsigned short* Bp = Ap + (size_t)B_ * NBOX * KP;      // 256 x 37632
  float* Cpart  = (float*)(Bp + (size_t)HID * KP);       // KSP x 1600 x 256 f32
  float* tokens = Cpart + (size_t)KSP * B_ * NBOX * HID; // 1600 x 256 f32
  float* ctx    = tokens + (size_t)B_ * NBOX * HID;      // 16 x 256 f32

  roi_pool_kernel<<<B_ * NBOX * 32, 64, 0, stream>>>(feat, boxes, Ap);
  wconv_kernel   <<<(HID * ROI_DIM) / 256, 256, 0, stream>>>(w_roi, Bp);
  gemm_kernel    <<<dim3((B_ * NBOX) / GBM, KSP), 256, 0, stream>>>(Ap, Bp, Cpart);
  reduce_kernel  <<<(B_ * NBOX * HID) / 256, 256, 0, stream>>>(Cpart, b_roi, tokens);
  attn_kernel    <<<B_ * 4, 256, 0, stream>>>(tokens, sev_q, w_in, b_in, ctx);
  mlp_kernel     <<<B_, 256, 0, stream>>>(ctx, w_out, b_out, ln_g, ln_b,
                                          w1, b1, w2, b2, out);
}

// Round 14
// 316.889 us; speedup vs baseline: 1.3665x; 1.1833x over previous
//
#include <hip/hip_runtime.h>
#include <math.h>

#define B_    16
#define C_    256
#define H_    200
#define W_    200
#define NBOX  100
#define HID   256
#define OUTK  7
#define ROI_DIM 12544        // C_ * 49
#define KP    25088          // 2 * ROI_DIM  (2-plane split: [ah,al] x [bh,bh] = a*bh)
#define NCLS  4

struct __attribute__((packed, aligned(4))) f2u { float x, y; };

typedef __attribute__((ext_vector_type(8))) short short8v;
typedef __attribute__((ext_vector_type(4))) float f32x4;

static __device__ __forceinline__ unsigned short f2bf(float f) {
  unsigned u = __float_as_uint(f);
  return (unsigned short)((u + 0x7FFFu + ((u >> 16) & 1u)) >> 16);   // RNE
}
static __device__ __forceinline__ float bf2f(unsigned short h) {
  return __uint_as_float(((unsigned)h) << 16);
}

static __device__ __forceinline__ void gload_lds4(const void* g, void* l) {
  __builtin_amdgcn_global_load_lds(
      (const __attribute__((address_space(1))) unsigned*)g,
      (__attribute__((address_space(3))) unsigned*)l, 4, 0, 0);
}

// ---------------------------------------------------------------- K1: ROI align — R7 structure, L2-epoch dispatch (FROZEN at ~295us:
// 1.63GB touched / 295us = 5.6 TB/s = ~89% of achievable load BW -> roofline).
// Output now 2-plane split-bf16: one coalesced u32 store {ah | al<<16}.
__global__ __launch_bounds__(64) void roi_pool_kernel(
    const float* __restrict__ feat, const float* __restrict__ boxes,
    unsigned* __restrict__ Ap32)
{
  constexpr int SPP = 66;
  __shared__ float tile[2][28][SPP];   // 14.8 KB, wave-private
  __shared__ int   rowoff_s[28];
  __shared__ int   ixs_s[14];
  __shared__ float flys_s[14], flxs_s[14];

  int raw  = blockIdx.x;
  int g16  = raw & 15;          // 8-channel group within half; g16%8 == XCD
  int rest = raw >> 4;          // 0..3199
  int bn_l = rest % NBOX;
  int ih   = rest / NBOX;       // 0..31 = (img, half)
  int half = ih & 1;
  int b    = ih >> 1;
  int bn   = b * NBOX + bn_l;

  const float* bx = boxes + (size_t)bn * 4;
  float px1 = bx[0] - 0.5f, py1 = bx[1] - 0.5f;
  float px2 = bx[2] - 0.5f, py2 = bx[3] - 0.5f;
  float bh = (py2 - py1) * (1.0f / OUTK);
  float bw = (px2 - px1) * (1.0f / OUTK);

  int lane = threadIdx.x;
  if (lane < 14) {
    int i = lane >> 1, s = lane & 1;
    float yy = py1 + ((float)i + ((float)s + 0.5f) * 0.5f) * bh;
    float yc = fminf(fmaxf(yy, 0.0f), (float)(H_ - 1));
    int y0 = min((int)floorf(yc), H_ - 2);
    rowoff_s[2 * lane]     = y0 * W_;
    rowoff_s[2 * lane + 1] = y0 * W_ + W_;
    flys_s[lane] = yc - (float)y0;
  } else if (lane >= 16 && lane < 30) {
    int t = lane - 16;
    int j = t >> 1, s = t & 1;
    float xx = px1 + ((float)j + ((float)s + 0.5f) * 0.5f) * bw;
    float xc = fminf(fmaxf(xx, 0.0f), (float)(W_ - 1));
    int x0 = min((int)floorf(xc), W_ - 2);
    ixs_s[t]  = x0;
    flxs_s[t] = xc - (float)x0;
  }
  asm volatile("s_waitcnt lgkmcnt(0)" ::: "memory");   // same-wave table visibility

  int xlo  = ixs_s[0];
  int span = ixs_s[13] + 2 - xlo;      // <= 64
  bool ld  = lane < span;

  int voff[28];                        // per-lane global byte offsets
  #pragma unroll
  for (int r = 0; r < 28; ++r) voff[r] = (rowoff_s[r] + xlo + lane) * 4;

  // per-lane bin constants, reused across all 8 channels
  int l49 = lane < 49 ? lane : 0;
  int bi = l49 / 7, bj = l49 - bi * 7;
  float ly0 = flys_s[2 * bi],     hy0 = 1.0f - ly0;
  float ly1 = flys_s[2 * bi + 1], hy1 = 1.0f - ly1;
  float lx0 = flxs_s[2 * bj],     hx0 = 1.0f - lx0;
  float lx1 = flxs_s[2 * bj + 1], hx1 = 1.0f - lx1;
  int xo0 = ixs_s[2 * bj] - xlo;
  int xo1 = ixs_s[2 * bj + 1] - xlo;
  int r0  = 4 * bi;

  int c0 = half * 128 + g16 * 8;       // wave's first channel
  const char* fc = (const char*)(feat + (size_t)b * (C_ * H_ * W_) + (size_t)c0 * (H_ * W_));
  unsigned* pw = Ap32 + (size_t)bn * ROI_DIM + (size_t)(c0 * 49 + l49);

  if (ld) {                            // prologue: DMA channel 0 -> buf0
    #pragma unroll
    for (int r = 0; r < 28; ++r) gload_lds4(fc + voff[r], &tile[0][r][0]);
  }

  #pragma unroll 1
  for (int n = 0; n < 8; ++n) {
    if (n < 7) {                       // issue next channel's DMA -> other buffer
      const char* fn = fc + (size_t)(n + 1) * (H_ * W_ * 4);
      if (ld) {
        #pragma unroll
        for (int r = 0; r < 28; ++r) gload_lds4(fn + voff[r], &tile[(n + 1) & 1][r][0]);
      }
      asm volatile("s_waitcnt vmcnt(28)" ::: "memory");   // current channel ready
    } else {
      asm volatile("s_waitcnt vmcnt(0)" ::: "memory");
    }
    float (*T)[SPP] = tile[n & 1];
    if (lane < 49) {
      f2u a0 = *(const f2u*)&T[r0 + 0][xo0];
      f2u a1 = *(const f2u*)&T[r0 + 1][xo0];
      f2u b0 = *(const f2u*)&T[r0 + 0][xo1];
      f2u b1 = *(const f2u*)&T[r0 + 1][xo1];
      f2u c2 = *(const f2u*)&T[r0 + 2][xo0];
      f2u c3 = *(const f2u*)&T[r0 + 3][xo0];
      f2u d2 = *(const f2u*)&T[r0 + 2][xo1];
      f2u d3 = *(const f2u*)&T[r0 + 3][xo1];
      float sum = hy0 * (hx0 * a0.x + lx0 * a0.y) + ly0 * (hx0 * a1.x + lx0 * a1.y)
                + hy0 * (hx1 * b0.x + lx1 * b0.y) + ly0 * (hx1 * b1.x + lx1 * b1.y)
                + hy1 * (hx0 * c2.x + lx0 * c2.y) + ly1 * (hx0 * c3.x + lx0 * c3.y)
                + hy1 * (hx1 * d2.x + lx1 * d2.y) + ly1 * (hx1 * d3.x + lx1 * d3.y);
      float s = sum * 0.25f;
      unsigned short hi = f2bf(s);
      unsigned short lo = f2bf(s - bf2f(hi));
      pw[0] = (unsigned)hi | ((unsigned)lo << 16);   // A'[2k]=ah, A'[2k+1]=al
    }
    pw += 49;
  }
}

// ---------------------------------------------------------------- K1b: w_roi -> B' = [bh, bh] (k-interleaved dup)
__global__ __launch_bounds__(256) void wconv_kernel(
    const float* __restrict__ w, unsigned* __restrict__ Bp32)
{
  int i = blockIdx.x * 256 + threadIdx.x;     // over 256*12544
  unsigned short hi = f2bf(w[i]);
  Bp32[i] = (unsigned)hi | ((unsigned)hi << 16);
}

// ---------------------------------------------------------------- K3: bf16 MFMA GEMM, full-N tile, partials (no atomics)
#define GBM 64
#define GBN 256
#define GBK 64
#define KSP 14
#define KT  28        // (KP/GBK)/KSP = 392/14
__global__ __launch_bounds__(256) void gemm_kernel(
    const unsigned short* __restrict__ Ap,
    const unsigned short* __restrict__ Bp,
    float* __restrict__ Cpart)
{
  __shared__ __align__(16) short As[GBM * GBK];   // 8 KB, swizzled chunks
  __shared__ __align__(16) short Bs[GBN * GBK];   // 32 KB

  int tid  = threadIdx.x;
  int lane = tid & 63;
  int w    = tid >> 6;
  int wr   = w >> 1, wc = w & 1;          // wave: rows wr*32, cols wc*128
  int m0 = blockIdx.x * GBM;
  int z  = blockIdx.y;
  int kbase = z * (GBK * KT);

  f32x4 acc[2][8];
  #pragma unroll
  for (int mi = 0; mi < 2; ++mi)
    #pragma unroll
    for (int nj = 0; nj < 8; ++nj)
      acc[mi][nj] = (f32x4){0.f, 0.f, 0.f, 0.f};

  for (int kt = 0; kt < KT; ++kt) {
    int kg = kbase + kt * GBK;
    __syncthreads();
    #pragma unroll
    for (int r = 0; r < 2; ++r) {          // stage A: 512 chunks of 16B
      int q = tid + r * 256;
      int row = q >> 3, c16 = q & 7;
      int kc16 = c16 ^ (row & 7);
      short8v v = *(const short8v*)(Ap + (size_t)(m0 + row) * KP + kg + kc16 * 8);
      *(short8v*)(As + row * GBK + c16 * 8) = v;
    }
    #pragma unroll
    for (int r = 0; r < 8; ++r) {          // stage B: 2048 chunks (all 256 rows)
      int q = tid + r * 256;
      int row = q >> 3, c16 = q & 7;
      int kc16 = c16 ^ (row & 7);
      short8v v = *(const short8v*)(Bp + (size_t)row * KP + kg + kc16 * 8);
      *(short8v*)(Bs + row * GBK + c16 * 8) = v;
    }
    __syncthreads();
    #pragma unroll
    for (int kk = 0; kk < 2; ++kk) {       // two K=32 steps per tile
      short8v af[2], bf[8];
      #pragma unroll
      for (int mi = 0; mi < 2; ++mi) {
        int row = wr * 32 + mi * 16 + (lane & 15);
        int c16 = (kk * 4 + (lane >> 4)) ^ (row & 7);
        af[mi] = *(const short8v*)(As + row * GBK + c16 * 8);
      }
      #pragma unroll
      for (int nj = 0; nj < 8; ++nj) {
        int row = wc * 128 + nj * 16 + (lane & 15);
        int c16 = (kk * 4 + (lane >> 4)) ^ (row & 7);
        bf[nj] = *(const short8v*)(Bs + row * GBK + c16 * 8);
      }
      #pragma unroll
      for (int mi = 0; mi < 2; ++mi)
        #pragma unroll
        for (int nj = 0; nj < 8; ++nj)
          acc[mi][nj] = __builtin_amdgcn_mfma_f32_16x16x32_bf16(
              af[mi], bf[nj], acc[mi][nj], 0, 0, 0);
    }
  }
  // epilogue: plain stores to partial buffer (D col=lane&15, row=(lane>>4)*4+reg)
  float* part = Cpart + (size_t)z * (B_ * NBOX * HID);
  int cn = lane & 15, rg = lane >> 4;
  #pragma unroll
  for (int mi = 0; mi < 2; ++mi)
    #pragma unroll
    for (int nj = 0; nj < 8; ++nj)
      #pragma unroll
      for (int r = 0; r < 4; ++r) {
        int row = m0 + wr * 32 + mi * 16 + rg * 4 + r;
        int col = wc * 128 + nj * 16 + cn;
        part[(size_t)row * HID + col] = acc[mi][nj][r];
      }
}

// ---------------------------------------------------------------- K3b: tokens = bias + sum of partials (float4)
__global__ __launch_bounds__(256) void reduce_kernel(
    const float* __restrict__ Cpart, const float* __restrict__ b_roi,
    float* __restrict__ tokens)
{
  int i = blockIdx.x * 256 + threadIdx.x;   // over 102400 float4s
  const float4* bias4 = (const float4*)b_roi;
  float4 a = bias4[i & 63];
  const float4* cp = (const float4*)Cpart;
  #pragma unroll
  for (int z = 0; z < KSP; ++z) {
    float4 p = cp[(size_t)z * (B_ * NBOX * HID / 4) + i];
    a.x += p.x; a.y += p.y; a.z += p.z; a.w += p.w;
  }
  ((float4*)tokens)[i] = a;
}

// ---------------------------------------------------------------- K4a: attention per (batch, head) -> ctx
__global__ __launch_bounds__(256) void attn_kernel(
    const float* __restrict__ tokens, const float* __restrict__ sev_q,
    const float* __restrict__ w_in,  const float* __restrict__ b_in,
    float* __restrict__ ctx)
{
  __shared__ float qh_s[64], qkv_s[256], att_s[128], tbar_s[256], red_s[2];
  int bh = blockIdx.x;
  int b = bh >> 2, h = bh & 3;
  int tid = threadIdx.x;
  const float* tok = tokens + (size_t)b * NBOX * HID;

  if (tid < 64) {                      // qh[d] = sev_q . Wq[h*64+d] + bq
    const float* wq = w_in + (size_t)(h * 64 + tid) * HID;
    float a = 0.0f;
    for (int e = 0; e < HID; ++e) a += sev_q[e] * wq[e];
    qh_s[tid] = a + b_in[h * 64 + tid];
  }
  __syncthreads();
  {                                    // qkv[e] = sum_d qh[d] * Wk[h*64+d][e]
    float a = 0.0f;
    for (int d = 0; d < 64; ++d)
      a += qh_s[d] * w_in[(size_t)(256 + h * 64 + d) * HID + tid];
    qkv_s[tid] = a;
  }
  if (tid == 0) {                      // qkb
    float a = 0.0f;
    for (int d = 0; d < 64; ++d) a += qh_s[d] * b_in[256 + h * 64 + d];
    red_s[0] = a;
  }
  __syncthreads();
  if (tid < NBOX) {                    // scores
    const float4* tr = (const float4*)(tok + (size_t)tid * HID);
    const float4* qv = (const float4*)qkv_s;
    float a = 0.0f;
    for (int e = 0; e < 64; ++e) {
      float4 t4 = tr[e], q4 = qv[e];
      a += t4.x * q4.x + t4.y * q4.y + t4.z * q4.z + t4.w * q4.w;
    }
    att_s[tid] = (a + red_s[0]) * 0.125f;
  }
  __syncthreads();
  if (tid == 0) {                      // softmax (serial; 100 elems)
    float mx = -1e30f;
    for (int t = 0; t < NBOX; ++t) mx = fmaxf(mx, att_s[t]);
    float sm = 0.0f;
    for (int t = 0; t < NBOX; ++t) { float e = expf(att_s[t] - mx); att_s[t] = e; sm += e; }
    red_s[1] = 1.0f / sm;
  }
  __syncthreads();
  {                                    // tbar[e] = inv * sum_t att[t]*tok[t][e]
    float a = 0.0f;
    for (int t = 0; t < NBOX; ++t) a += att_s[t] * tok[(size_t)t * HID + tid];
    tbar_s[tid] = a * red_s[1];
  }
  __syncthreads();
  if (tid < 64) {                      // ctx[h*64+d] = tbar . Wv[h*64+d] + bv
    const float* wv = w_in + (size_t)(512 + h * 64 + tid) * HID;
    float a = 0.0f;
    for (int e = 0; e < HID; ++e) a += tbar_s[e] * wv[e];
    ctx[(size_t)b * HID + h * 64 + tid] = a + b_in[512 + h * 64 + tid];
  }
}

// ---------------------------------------------------------------- K4b: Wout + LayerNorm + MLP per batch
__global__ __launch_bounds__(256) void mlp_kernel(
    const float* __restrict__ ctx,
    const float* __restrict__ w_out, const float* __restrict__ b_out,
    const float* __restrict__ ln_g,  const float* __restrict__ ln_b,
    const float* __restrict__ w1,    const float* __restrict__ b1,
    const float* __restrict__ w2,    const float* __restrict__ b2,
    float* __restrict__ outp)
{
  __shared__ float o_s[256], x_s[256], h1_s[256], red_s[8];
  int b = blockIdx.x, tid = threadIdx.x;
  const float* cx = ctx + (size_t)b * HID;
  {
    const float* wo = w_out + (size_t)tid * HID;
    float a = 0.0f;
    for (int k = 0; k < HID; ++k) a += cx[k] * wo[k];
    o_s[tid] = a + b_out[tid];
  }
  __syncthreads();
  {
    float v = o_s[tid];
    float s1 = v, s2 = v * v;
    #pragma unroll
    for (int off = 32; off > 0; off >>= 1) {
      s1 += __shfl_down(s1, off);
      s2 += __shfl_down(s2, off);
    }
    if ((tid & 63) == 0) { red_s[(tid >> 6) * 2] = s1; red_s[(tid >> 6) * 2 + 1] = s2; }
    __syncthreads();
    float sum = red_s[0] + red_s[2] + red_s[4] + red_s[6];
    float ssq = red_s[1] + red_s[3] + red_s[5] + red_s[7];
    float mu  = sum * (1.0f / 256.0f);
    float var = ssq * (1.0f / 256.0f) - mu * mu;
    float inv = rsqrtf(var + 1e-5f);
    x_s[tid] = (v - mu) * inv * ln_g[tid] + ln_b[tid];
  }
  __syncthreads();
  {
    const float* wr = w1 + (size_t)tid * HID;
    float a = 0.0f;
    for (int k = 0; k < HID; ++k) a += x_s[k] * wr[k];
    h1_s[tid] = fmaxf(a + b1[tid], 0.0f);
  }
  __syncthreads();
  if (tid < NCLS) {
    const float* wr = w2 + (size_t)tid * HID;
    float a = 0.0f;
    for (int k = 0; k < HID; ++k) a += h1_s[k] * wr[k];
    outp[b * NCLS + tid] = a + b2[tid];
  }
}

// ---------------------------------------------------------------- launch
extern "C" void kernel_launch(void* const* d_in, const int* in_sizes, int n_in,
                              void* d_out, int out_size, void* d_ws, size_t ws_size,
                              hipStream_t stream) {
  (void)in_sizes; (void)n_in; (void)out_size; (void)ws_size;
  const float* feat  = (const float*)d_in[0];
  const float* boxes = (const float*)d_in[1];
  const float* w_roi = (const float*)d_in[2];
  const float* b_roi = (const float*)d_in[3];
  const float* sev_q = (const float*)d_in[4];
  const float* w_in  = (const float*)d_in[5];
  const float* b_in  = (const float*)d_in[6];
  const float* w_out = (const float*)d_in[7];
  const float* b_out = (const float*)d_in[8];
  const float* ln_g  = (const float*)d_in[9];
  const float* ln_b  = (const float*)d_in[10];
  const float* w1    = (const float*)d_in[11];
  const float* b1    = (const float*)d_in[12];
  const float* w2    = (const float*)d_in[13];
  const float* b2    = (const float*)d_in[14];
  float* out = (float*)d_out;

  unsigned short* Ap = (unsigned short*)d_ws;            // 1600 x 25088 split-bf16
  unsigned short* Bp = Ap + (size_t)B_ * NBOX * KP;      // 256 x 25088
  float* Cpart  = (float*)(Bp + (size_t)HID * KP);       // KSP x 1600 x 256 f32
  float* tokens = Cpart + (size_t)KSP * B_ * NBOX * HID; // 1600 x 256 f32
  float* ctx    = tokens + (size_t)B_ * NBOX * HID;      // 16 x 256 f32

  roi_pool_kernel<<<B_ * NBOX * 32, 64, 0, stream>>>(feat, boxes, (unsigned*)Ap);
  wconv_kernel   <<<(HID * ROI_DIM) / 256, 256, 0, stream>>>(w_roi, (unsigned*)Bp);
  gemm_kernel    <<<dim3((B_ * NBOX) / GBM, KSP), 256, 0, stream>>>(Ap, Bp, Cpart);
  reduce_kernel  <<<(B_ * NBOX * HID / 4) / 256, 256, 0, stream>>>(Cpart, b_roi, tokens);
  attn_kernel    <<<B_ * 4, 256, 0, stream>>>(tokens, sev_q, w_in, b_in, ctx);
  mlp_kernel     <<<B_, 256, 0, stream>>>(ctx, w_out, b_out, ln_g, ln_b,
                                          w1, b1, w2, b2, out);
}

// Round 15
// 301.661 us; speedup vs baseline: 1.4355x; 1.0505x over previous
//
#include <hip/hip_runtime.h>
#include <math.h>

#define B_    16
#define C_    256
#define H_    200
#define W_    200
#define NBOX  100
#define HID   256
#define OUTK  7
#define ROI_DIM 12544        // C_ * 49
#define KP    25088          // 2 * ROI_DIM  (2-plane split: [ah,al] x [bh,bh] = a*bh)
#define NCLS  4

struct __attribute__((packed, aligned(4))) f2u { float x, y; };

typedef __attribute__((ext_vector_type(8))) short short8v;
typedef __attribute__((ext_vector_type(4))) float f32x4;

static __device__ __forceinline__ unsigned short f2bf(float f) {
  unsigned u = __float_as_uint(f);
  return (unsigned short)((u + 0x7FFFu + ((u >> 16) & 1u)) >> 16);   // RNE
}
static __device__ __forceinline__ float bf2f(unsigned short h) {
  return __uint_as_float(((unsigned)h) << 16);
}

// ---------------------------------------------------------------- K1: ROI align — full channel map resident in LDS
// Block = (img, ch), 1024 threads, 156.25 KiB dynamic LDS = the whole 200x200
// map. Phase 1: one coalesced 160KB linear copy (feat read ONCE -> 655 MB
// total, the unique-byte floor; was 1.63 GB of scattered re-reads). Phase 2:
// 4900 (box,bin) items gathered from LDS (8 ds_read per item, ~5 items/thread,
// per-item register tables). No spans, no windows, no per-box staging.
__global__ __launch_bounds__(1024) void roi_pool_kernel(
    const float* __restrict__ feat, const float* __restrict__ boxes,
    unsigned* __restrict__ Ap32)
{
  extern __shared__ float lmap[];     // 200*200 floats = 160000 B
  int bid = blockIdx.x;
  int img = bid >> 8;                 // 0..15
  int ch  = bid & 255;
  int tid = threadIdx.x;

  // ---- phase 1: stage the full channel map (10000 float4s)
  const float4* src = (const float4*)(feat + ((size_t)img * C_ + ch) * (H_ * W_));
  float4* dst = (float4*)lmap;
  #pragma unroll
  for (int r = 0; r < 9; ++r) dst[tid + r * 1024] = src[tid + r * 1024];
  if (tid < 10000 - 9 * 1024) dst[tid + 9 * 1024] = src[tid + 9 * 1024];
  __syncthreads();

  const float* bxb = boxes + (size_t)img * NBOX * 4;
  unsigned* ap = Ap32 + (size_t)img * NBOX * ROI_DIM + ch * 49;

  // ---- phase 2: gather 100 boxes x 49 bins from LDS
  #pragma unroll 1
  for (int it = tid; it < NBOX * 49; it += 1024) {
    int box = it / 49;
    int bin = it - box * 49;
    int bi  = bin / 7;
    int bj  = bin - bi * 7;

    const float* bx = bxb + box * 4;
    float x1 = bx[0] - 0.5f, y1 = bx[1] - 0.5f;
    float bw = (bx[2] - 0.5f - x1) * (1.0f / 7.0f);
    float bh = (bx[3] - 0.5f - y1) * (1.0f / 7.0f);

    int   yr[2]; float wy0[2], wy1[2];
    #pragma unroll
    for (int s = 0; s < 2; ++s) {
      float yy = y1 + ((float)bi + 0.25f + 0.5f * (float)s) * bh;
      float yc = fminf(fmaxf(yy, 0.0f), 199.0f);
      int y0 = min((int)yc, 198);          // yc>=0: trunc == floor
      float ly = yc - (float)y0;
      yr[s] = y0 * W_;
      wy0[s] = 1.0f - ly; wy1[s] = ly;
    }
    int xc_[2]; float hx[2], lx[2];
    #pragma unroll
    for (int s = 0; s < 2; ++s) {
      float xx = x1 + ((float)bj + 0.25f + 0.5f * (float)s) * bw;
      float xc = fminf(fmaxf(xx, 0.0f), 199.0f);
      int x0 = min((int)xc, 198);
      lx[s] = xc - (float)x0;
      hx[s] = 1.0f - lx[s];
      xc_[s] = x0;
    }
    float sum = 0.0f;
    #pragma unroll
    for (int sy = 0; sy < 2; ++sy) {
      #pragma unroll
      for (int sx = 0; sx < 2; ++sx) {
        f2u t0 = *(const f2u*)&lmap[yr[sy] + xc_[sx]];
        f2u t1 = *(const f2u*)&lmap[yr[sy] + W_ + xc_[sx]];
        sum += wy0[sy] * (hx[sx] * t0.x + lx[sx] * t0.y)
             + wy1[sy] * (hx[sx] * t1.x + lx[sx] * t1.y);
      }
    }
    float s = sum * 0.25f;
    unsigned short hi = f2bf(s);
    unsigned short lo = f2bf(s - bf2f(hi));
    ap[(size_t)box * ROI_DIM + bin] = (unsigned)hi | ((unsigned)lo << 16);
  }
}

// ---------------------------------------------------------------- K1b: w_roi -> B' = [bh, bh] (k-interleaved dup)
__global__ __launch_bounds__(256) void wconv_kernel(
    const float* __restrict__ w, unsigned* __restrict__ Bp32)
{
  int i = blockIdx.x * 256 + threadIdx.x;     // over 256*12544
  unsigned short hi = f2bf(w[i]);
  Bp32[i] = (unsigned)hi | ((unsigned)hi << 16);
}

// ---------------------------------------------------------------- K3: bf16 MFMA GEMM, full-N tile, partials (no atomics)
#define GBM 64
#define GBN 256
#define GBK 64
#define KSP 14
#define KT  28        // (KP/GBK)/KSP = 392/14
__global__ __launch_bounds__(256) void gemm_kernel(
    const unsigned short* __restrict__ Ap,
    const unsigned short* __restrict__ Bp,
    float* __restrict__ Cpart)
{
  __shared__ __align__(16) short As[GBM * GBK];   // 8 KB, swizzled chunks
  __shared__ __align__(16) short Bs[GBN * GBK];   // 32 KB

  int tid  = threadIdx.x;
  int lane = tid & 63;
  int w    = tid >> 6;
  int wr   = w >> 1, wc = w & 1;          // wave: rows wr*32, cols wc*128
  int m0 = blockIdx.x * GBM;
  int z  = blockIdx.y;
  int kbase = z * (GBK * KT);

  f32x4 acc[2][8];
  #pragma unroll
  for (int mi = 0; mi < 2; ++mi)
    #pragma unroll
    for (int nj = 0; nj < 8; ++nj)
      acc[mi][nj] = (f32x4){0.f, 0.f, 0.f, 0.f};

  for (int kt = 0; kt < KT; ++kt) {
    int kg = kbase + kt * GBK;
    __syncthreads();
    #pragma unroll
    for (int r = 0; r < 2; ++r) {          // stage A: 512 chunks of 16B
      int q = tid + r * 256;
      int row = q >> 3, c16 = q & 7;
      int kc16 = c16 ^ (row & 7);
      short8v v = *(const short8v*)(Ap + (size_t)(m0 + row) * KP + kg + kc16 * 8);
      *(short8v*)(As + row * GBK + c16 * 8) = v;
    }
    #pragma unroll
    for (int r = 0; r < 8; ++r) {          // stage B: 2048 chunks (all 256 rows)
      int q = tid + r * 256;
      int row = q >> 3, c16 = q & 7;
      int kc16 = c16 ^ (row & 7);
      short8v v = *(const short8v*)(Bp + (size_t)row * KP + kg + kc16 * 8);
      *(short8v*)(Bs + row * GBK + c16 * 8) = v;
    }
    __syncthreads();
    #pragma unroll
    for (int kk = 0; kk < 2; ++kk) {       // two K=32 steps per tile
      short8v af[2], bf[8];
      #pragma unroll
      for (int mi = 0; mi < 2; ++mi) {
        int row = wr * 32 + mi * 16 + (lane & 15);
        int c16 = (kk * 4 + (lane >> 4)) ^ (row & 7);
        af[mi] = *(const short8v*)(As + row * GBK + c16 * 8);
      }
      #pragma unroll
      for (int nj = 0; nj < 8; ++nj) {
        int row = wc * 128 + nj * 16 + (lane & 15);
        int c16 = (kk * 4 + (lane >> 4)) ^ (row & 7);
        bf[nj] = *(const short8v*)(Bs + row * GBK + c16 * 8);
      }
      #pragma unroll
      for (int mi = 0; mi < 2; ++mi)
        #pragma unroll
        for (int nj = 0; nj < 8; ++nj)
          acc[mi][nj] = __builtin_amdgcn_mfma_f32_16x16x32_bf16(
              af[mi], bf[nj], acc[mi][nj], 0, 0, 0);
    }
  }
  // epilogue: plain stores to partial buffer (D col=lane&15, row=(lane>>4)*4+reg)
  float* part = Cpart + (size_t)z * (B_ * NBOX * HID);
  int cn = lane & 15, rg = lane >> 4;
  #pragma unroll
  for (int mi = 0; mi < 2; ++mi)
    #pragma unroll
    for (int nj = 0; nj < 8; ++nj)
      #pragma unroll
      for (int r = 0; r < 4; ++r) {
        int row = m0 + wr * 32 + mi * 16 + rg * 4 + r;
        int col = wc * 128 + nj * 16 + cn;
        part[(size_t)row * HID + col] = acc[mi][nj][r];
      }
}

// ---------------------------------------------------------------- K3b: tokens = bias + sum of partials (float4)
__global__ __launch_bounds__(256) void reduce_kernel(
    const float* __restrict__ Cpart, const float* __restrict__ b_roi,
    float* __restrict__ tokens)
{
  int i = blockIdx.x * 256 + threadIdx.x;   // over 102400 float4s
  const float4* bias4 = (const float4*)b_roi;
  float4 a = bias4[i & 63];
  const float4* cp = (const float4*)Cpart;
  #pragma unroll
  for (int z = 0; z < KSP; ++z) {
    float4 p = cp[(size_t)z * (B_ * NBOX * HID / 4) + i];
    a.x += p.x; a.y += p.y; a.z += p.z; a.w += p.w;
  }
  ((float4*)tokens)[i] = a;
}

// ---------------------------------------------------------------- K4a: attention per (batch, head) -> ctx
__global__ __launch_bounds__(256) void attn_kernel(
    const float* __restrict__ tokens, const float* __restrict__ sev_q,
    const float* __restrict__ w_in,  const float* __restrict__ b_in,
    float* __restrict__ ctx)
{
  __shared__ float qh_s[64], qkv_s[256], att_s[128], tbar_s[256], red_s[2];
  int bh = blockIdx.x;
  int b = bh >> 2, h = bh & 3;
  int tid = threadIdx.x;
  const float* tok = tokens + (size_t)b * NBOX * HID;

  if (tid < 64) {                      // qh[d] = sev_q . Wq[h*64+d] + bq
    const float* wq = w_in + (size_t)(h * 64 + tid) * HID;
    float a = 0.0f;
    for (int e = 0; e < HID; ++e) a += sev_q[e] * wq[e];
    qh_s[tid] = a + b_in[h * 64 + tid];
  }
  __syncthreads();
  {                                    // qkv[e] = sum_d qh[d] * Wk[h*64+d][e]
    float a = 0.0f;
    for (int d = 0; d < 64; ++d)
      a += qh_s[d] * w_in[(size_t)(256 + h * 64 + d) * HID + tid];
    qkv_s[tid] = a;
  }
  if (tid == 0) {                      // qkb
    float a = 0.0f;
    for (int d = 0; d < 64; ++d) a += qh_s[d] * b_in[256 + h * 64 + d];
    red_s[0] = a;
  }
  __syncthreads();
  if (tid < NBOX) {                    // scores
    const float4* tr = (const float4*)(tok + (size_t)tid * HID);
    const float4* qv = (const float4*)qkv_s;
    float a = 0.0f;
    for (int e = 0; e < 64; ++e) {
      float4 t4 = tr[e], q4 = qv[e];
      a += t4.x * q4.x + t4.y * q4.y + t4.z * q4.z + t4.w * q4.w;
    }
    att_s[tid] = (a + red_s[0]) * 0.125f;
  }
  __syncthreads();
  if (tid == 0) {                      // softmax (serial; 100 elems)
    float mx = -1e30f;
    for (int t = 0; t < NBOX; ++t) mx = fmaxf(mx, att_s[t]);
    float sm = 0.0f;
    for (int t = 0; t < NBOX; ++t) { float e = expf(att_s[t] - mx); att_s[t] = e; sm += e; }
    red_s[1] = 1.0f / sm;
  }
  __syncthreads();
  {                                    // tbar[e] = inv * sum_t att[t]*tok[t][e]
    float a = 0.0f;
    for (int t = 0; t < NBOX; ++t) a += att_s[t] * tok[(size_t)t * HID + tid];
    tbar_s[tid] = a * red_s[1];
  }
  __syncthreads();
  if (tid < 64) {                      // ctx[h*64+d] = tbar . Wv[h*64+d] + bv
    const float* wv = w_in + (size_t)(512 + h * 64 + tid) * HID;
    float a = 0.0f;
    for (int e = 0; e < HID; ++e) a += tbar_s[e] * wv[e];
    ctx[(size_t)b * HID + h * 64 + tid] = a + b_in[512 + h * 64 + tid];
  }
}

// ---------------------------------------------------------------- K4b: Wout + LayerNorm + MLP per batch
__global__ __launch_bounds__(256) void mlp_kernel(
    const float* __restrict__ ctx,
    const float* __restrict__ w_out, const float* __restrict__ b_out,
    const float* __restrict__ ln_g,  const float* __restrict__ ln_b,
    const float* __restrict__ w1,    const float* __restrict__ b1,
    const float* __restrict__ w2,    const float* __restrict__ b2,
    float* __restrict__ outp)
{
  __shared__ float o_s[256], x_s[256], h1_s[256], red_s[8];
  int b = blockIdx.x, tid = threadIdx.x;
  const float* cx = ctx + (size_t)b * HID;
  {
    const float* wo = w_out + (size_t)tid * HID;
    float a = 0.0f;
    for (int k = 0; k < HID; ++k) a += cx[k] * wo[k];
    o_s[tid] = a + b_out[tid];
  }
  __syncthreads();
  {
    float v = o_s[tid];
    float s1 = v, s2 = v * v;
    #pragma unroll
    for (int off = 32; off > 0; off >>= 1) {
      s1 += __shfl_down(s1, off);
      s2 += __shfl_down(s2, off);
    }
    if ((tid & 63) == 0) { red_s[(tid >> 6) * 2] = s1; red_s[(tid >> 6) * 2 + 1] = s2; }
    __syncthreads();
    float sum = red_s[0] + red_s[2] + red_s[4] + red_s[6];
    float ssq = red_s[1] + red_s[3] + red_s[5] + red_s[7];
    float mu  = sum * (1.0f / 256.0f);
    float var = ssq * (1.0f / 256.0f) - mu * mu;
    float inv = rsqrtf(var + 1e-5f);
    x_s[tid] = (v - mu) * inv * ln_g[tid] + ln_b[tid];
  }
  __syncthreads();
  {
    const float* wr = w1 + (size_t)tid * HID;
    float a = 0.0f;
    for (int k = 0; k < HID; ++k) a += x_s[k] * wr[k];
    h1_s[tid] = fmaxf(a + b1[tid], 0.0f);
  }
  __syncthreads();
  if (tid < NCLS) {
    const float* wr = w2 + (size_t)tid * HID;
    float a = 0.0f;
    for (int k = 0; k < HID; ++k) a += h1_s[k] * wr[k];
    outp[b * NCLS + tid] = a + b2[tid];
  }
}

// ---------------------------------------------------------------- launch
extern "C" void kernel_launch(void* const* d_in, const int* in_sizes, int n_in,
                              void* d_out, int out_size, void* d_ws, size_t ws_size,
                              hipStream_t stream) {
  (void)in_sizes; (void)n_in; (void)out_size; (void)ws_size;
  const float* feat  = (const float*)d_in[0];
  const float* boxes = (const float*)d_in[1];
  const float* w_roi = (const float*)d_in[2];
  const float* b_roi = (const float*)d_in[3];
  const float* sev_q = (const float*)d_in[4];
  const float* w_in  = (const float*)d_in[5];
  const float* b_in  = (const float*)d_in[6];
  const float* w_out = (const float*)d_in[7];
  const float* b_out = (const float*)d_in[8];
  const float* ln_g  = (const float*)d_in[9];
  const float* ln_b  = (const float*)d_in[10];
  const float* w1    = (const float*)d_in[11];
  const float* b1    = (const float*)d_in[12];
  const float* w2    = (const float*)d_in[13];
  const float* b2    = (const float*)d_in[14];
  float* out = (float*)d_out;

  unsigned short* Ap = (unsigned short*)d_ws;            // 1600 x 25088 split-bf16
  unsigned short* Bp = Ap + (size_t)B_ * NBOX * KP;      // 256 x 25088
  float* Cpart  = (float*)(Bp + (size_t)HID * KP);       // KSP x 1600 x 256 f32
  float* tokens = Cpart + (size_t)KSP * B_ * NBOX * HID; // 1600 x 256 f32
  float* ctx    = tokens + (size_t)B_ * NBOX * HID;      // 16 x 256 f32

  roi_pool_kernel<<<B_ * C_, 1024, 160000, stream>>>(feat, boxes, (unsigned*)Ap);
  wconv_kernel   <<<(HID * ROI_DIM) / 256, 256, 0, stream>>>(w_roi, (unsigned*)Bp);
  gemm_kernel    <<<dim3((B_ * NBOX) / GBM, KSP), 256, 0, stream>>>(Ap, Bp, Cpart);
  reduce_kernel  <<<(B_ * NBOX * HID / 4) / 256, 256, 0, stream>>>(Cpart, b_roi, tokens);
  attn_kernel    <<<B_ * 4, 256, 0, stream>>>(tokens, sev_q, w_in, b_in, ctx);
  mlp_kernel     <<<B_, 256, 0, stream>>>(ctx, w_out, b_out, ln_g, ln_b,
                                          w1, b1, w2, b2, out);
}